// Round 4
// baseline (530.710 us; speedup 1.0000x reference)
//
#include <hip/hip_runtime.h>
#include <hip/hip_bf16.h>

#define F 2048
#define MB 16384
#define BM 128
#define BN 128
#define BK 64
#define PLANE (BM * BK)   // 8192 shorts = 16 KB per plane (Ah or Al)

typedef short bf16x8 __attribute__((ext_vector_type(8)));  // 8 bf16 (4 VGPRs), MFMA A/B frag
typedef float f32x4 __attribute__((ext_vector_type(4)));   // MFMA C/D frag

static __device__ __forceinline__ unsigned short bfb(float v) {
    return __builtin_bit_cast(unsigned short, __float2bfloat16(v));
}
static __device__ __forceinline__ float bff(unsigned short u) {
    return __bfloat162float(__builtin_bit_cast(__hip_bfloat16, u));
}

// ---------------- build transposed upper-tri B planes (hi/lo bf16) ----------------
// Bt[j2*F + j1] = bw[pair(j1,j2)] if j1<j2 else 0.
__global__ __launch_bounds__(256) void build_bt(const float* __restrict__ bw,
                                                unsigned short* __restrict__ bt_hi,
                                                unsigned short* __restrict__ bt_lo) {
    int idx = blockIdx.x * 256 + threadIdx.x;   // idx over F*F, row-major [j2][j1]
    int j2 = idx >> 11;
    int j1 = idx & (F - 1);
    float v = 0.f;
    if (j1 < j2) {
        int k = j1 * F - ((j1 * (j1 + 1)) >> 1) + (j2 - j1 - 1);
        v = bw[k];
    }
    unsigned short h = bfb(v);
    bt_hi[idx] = h;
    bt_lo[idx] = bfb(v - bff(h));
}

// ---------------- main GEMM: y = x * B (upper-tri), fused epilogue ----------------
// A (x hi/lo) double-buffered in LDS, XOR-swizzled: 16B chunk (row, s) holds data
// chunk d = s ^ (row & 7).  B fragments load DIRECTLY global->reg (L2-resident bt,
// shared across all 128 mt-blocks per nt) — no B LDS traffic at all.
__global__ __launch_bounds__(256, 2) void poly2_gemm(
        const float* __restrict__ x,
        const unsigned short* __restrict__ bt_hi,
        const unsigned short* __restrict__ bt_lo,
        const float* __restrict__ w,
        float* __restrict__ cross_acc) {
    extern __shared__ unsigned short smem[];

    const int tid  = threadIdx.x;
    const int lane = tid & 63;
    const int wid  = tid >> 6;
    const int wm   = wid >> 1;      // 2x2 wave grid, each wave 64x64 out
    const int wn   = wid & 1;
    const int lr   = lane & 15;
    const int lg   = lane >> 4;

    // work-descending order: 128 consecutive blocks share the same bt columns
    const int nt = 15 - (blockIdx.x >> 7);
    const int mt = blockIdx.x & 127;
    const int m0 = mt * BM;
    const int n0 = nt * BN;
    const int ktiles = 2 * (nt + 1);        // triangular skip: kt*64 < (nt+1)*128

    f32x4 acc[4][4] = {};

    // ---- helpers ----
    // load the fp32 source chunks for next A tile (swizzle-permuted source order)
    auto loadA = [&](int k0, float4* av) {
#pragma unroll
        for (int r = 0; r < 4; ++r) {
            int q = r * 256 + tid;              // LDS chunk index (16B units)
            int row = q >> 3;
            int d = (q & 7) ^ (row & 7);        // data chunk stored at slot q&7
            const float* src = x + (size_t)(m0 + row) * F + (k0 + d * 8);
            av[r * 2 + 0] = ((const float4*)src)[0];
            av[r * 2 + 1] = ((const float4*)src)[1];
        }
    };
    // convert to bf16 hi/lo and store to LDS (linear chunk q -> conflict-free)
    auto writeA = [&](int buf, const float4* av) {
        unsigned short* Ah = smem + buf * 2 * PLANE;
        unsigned short* Al = Ah + PLANE;
#pragma unroll
        for (int r = 0; r < 4; ++r) {
            int q = r * 256 + tid;
            float vv[8] = {av[r*2].x, av[r*2].y, av[r*2].z, av[r*2].w,
                           av[r*2+1].x, av[r*2+1].y, av[r*2+1].z, av[r*2+1].w};
            unsigned hw[8], lw[8];
#pragma unroll
            for (int j = 0; j < 8; ++j) {
                unsigned short h = bfb(vv[j]);
                hw[j] = h;
                lw[j] = bfb(vv[j] - bff(h));
            }
            uint4 hp, lp;
            hp.x = hw[0] | (hw[1] << 16); hp.y = hw[2] | (hw[3] << 16);
            hp.z = hw[4] | (hw[5] << 16); hp.w = hw[6] | (hw[7] << 16);
            lp.x = lw[0] | (lw[1] << 16); lp.y = lw[2] | (lw[3] << 16);
            lp.z = lw[4] | (lw[5] << 16); lp.w = lw[6] | (lw[7] << 16);
            *(uint4*)&Ah[q * 8] = hp;
            *(uint4*)&Al[q * 8] = lp;
        }
    };
    // direct global->reg B fragments (16 cols x 32 k slice at k)
    auto loadB = [&](int k, bf16x8* bh, bf16x8* bl) {
#pragma unroll
        for (int n = 0; n < 4; ++n) {
            int c = n0 + wn * 64 + n * 16 + lr;
            size_t off = (size_t)c * F + k + lg * 8;
            bh[n] = *(const bf16x8*)(bt_hi + off);
            bl[n] = *(const bf16x8*)(bt_lo + off);
        }
    };

    bf16x8 b0h[4], b0l[4], b1h[4], b1l[4];

    // ---- prologue: fill buf 0, load first B frags ----
    {
        float4 av[8];
        loadA(0, av);
        writeA(0, av);
        loadB(0, b0h, b0l);
    }
    __syncthreads();

    int cur = 0;
    for (int kt = 0; kt < ktiles; ++kt) {
        const bool more = (kt + 1) < ktiles;
        unsigned short* Ah = smem + cur * 2 * PLANE;
        unsigned short* Al = Ah + PLANE;

        // issue next A-tile fp32 loads early (latency hides under 96 MFMAs)
        float4 av[8];
        if (more) loadA((kt + 1) * BK, av);

        // ---- kk = 0 : prefetch B(kt, kk=1), compute with b0 ----
        loadB(kt * BK + 32, b1h, b1l);
        {
            bf16x8 ah[4], al[4];
#pragma unroll
            for (int m = 0; m < 4; ++m) {
                int row = wm * 64 + m * 16 + lr;
                int s = lg ^ (lr & 7);              // kk=0 slots
                ah[m] = *(const bf16x8*)&Ah[row * 64 + s * 8];
                al[m] = *(const bf16x8*)&Al[row * 64 + s * 8];
            }
#pragma unroll
            for (int m = 0; m < 4; ++m)
#pragma unroll
                for (int n = 0; n < 4; ++n) {
                    acc[m][n] = __builtin_amdgcn_mfma_f32_16x16x32_bf16(ah[m], b0h[n], acc[m][n], 0, 0, 0);
                    acc[m][n] = __builtin_amdgcn_mfma_f32_16x16x32_bf16(ah[m], b0l[n], acc[m][n], 0, 0, 0);
                    acc[m][n] = __builtin_amdgcn_mfma_f32_16x16x32_bf16(al[m], b0h[n], acc[m][n], 0, 0, 0);
                }
        }

        // ---- kk = 1 : prefetch B(kt+1, kk=0), compute with b1 ----
        if (more) loadB((kt + 1) * BK, b0h, b0l);
        {
            bf16x8 ah[4], al[4];
#pragma unroll
            for (int m = 0; m < 4; ++m) {
                int row = wm * 64 + m * 16 + lr;
                int s = (4 + lg) ^ (lr & 7);        // kk=1 slots
                ah[m] = *(const bf16x8*)&Ah[row * 64 + s * 8];
                al[m] = *(const bf16x8*)&Al[row * 64 + s * 8];
            }
#pragma unroll
            for (int m = 0; m < 4; ++m)
#pragma unroll
                for (int n = 0; n < 4; ++n) {
                    acc[m][n] = __builtin_amdgcn_mfma_f32_16x16x32_bf16(ah[m], b1h[n], acc[m][n], 0, 0, 0);
                    acc[m][n] = __builtin_amdgcn_mfma_f32_16x16x32_bf16(ah[m], b1l[n], acc[m][n], 0, 0, 0);
                    acc[m][n] = __builtin_amdgcn_mfma_f32_16x16x32_bf16(al[m], b1h[n], acc[m][n], 0, 0, 0);
                }
        }

        // convert + LDS-write next A tile after MFMAs (T14 late-write)
        if (more) writeA(cur ^ 1, av);
        __syncthreads();
        cur ^= 1;
    }

    // ---- epilogue: (y + w) dot x per row, 16-lane shuffle reduce, atomic accumulate ----
#pragma unroll
    for (int m = 0; m < 4; ++m) {
#pragma unroll
        for (int r = 0; r < 4; ++r) {
            int grow = m0 + wm * 64 + m * 16 + lg * 4 + r;
            float sum = 0.f;
#pragma unroll
            for (int n = 0; n < 4; ++n) {
                int gcol = n0 + wn * 64 + n * 16 + lr;
                float y = acc[m][n][r] + w[gcol];
                sum += y * x[(size_t)grow * F + gcol];
            }
            sum += __shfl_xor(sum, 1);
            sum += __shfl_xor(sum, 2);
            sum += __shfl_xor(sum, 4);
            sum += __shfl_xor(sum, 8);
            if (lr == 0) atomicAdd(&cross_acc[grow], sum);
        }
    }
}

// ---------------- final sigmoid ----------------
__global__ __launch_bounds__(256) void finish_sigmoid(const float* __restrict__ cross,
                                                      const float* __restrict__ w0,
                                                      float* __restrict__ out) {
    int b = blockIdx.x * 256 + threadIdx.x;
    float z = cross[b] + w0[0];
    out[b] = 1.f / (1.f + expf(-z));
}

extern "C" void kernel_launch(void* const* d_in, const int* in_sizes, int n_in,
                              void* d_out, int out_size, void* d_ws, size_t ws_size,
                              hipStream_t stream) {
    const float* x  = (const float*)d_in[0];
    const float* w0 = (const float*)d_in[1];
    const float* w  = (const float*)d_in[2];
    const float* bw = (const float*)d_in[3];
    float* out = (float*)d_out;

    // ws layout: [cross_acc: MB f32][bt_hi: F*F bf16][bt_lo: F*F bf16]  (~16.9 MB)
    float* cross = (float*)d_ws;
    unsigned short* bt_hi = (unsigned short*)((char*)d_ws + (size_t)MB * sizeof(float));
    unsigned short* bt_lo = bt_hi + (size_t)F * F;

    hipMemsetAsync(cross, 0, (size_t)MB * sizeof(float), stream);
    build_bt<<<F * F / 256, 256, 0, stream>>>(bw, bt_hi, bt_lo);
    size_t smem = (size_t)(2 * 2 * PLANE) * sizeof(unsigned short);   // 64 KiB (A only)
    poly2_gemm<<<dim3((MB / BM) * (F / BN)), 256, smem, stream>>>(x, bt_hi, bt_lo, w, cross);
    finish_sigmoid<<<MB / 256, 256, 0, stream>>>(cross, w0, out);
}

// Round 5
// 392.581 us; speedup vs baseline: 1.3518x; 1.3518x over previous
//
#include <hip/hip_runtime.h>
#include <hip/hip_bf16.h>

#define F 2048
#define MBATCH 16384
#define BM 256
#define BN 256
#define BK 32
#define PL (BM * BK)          // shorts per plane (8192 = 16 KB)
#define THREADS 512

typedef short bf16x8 __attribute__((ext_vector_type(8)));  // MFMA A/B frag (4 VGPR)
typedef float f32x4 __attribute__((ext_vector_type(4)));   // MFMA C/D frag

static __device__ __forceinline__ unsigned short bfb(float v) {
    return __builtin_bit_cast(unsigned short, __float2bfloat16(v));
}
static __device__ __forceinline__ float bff(unsigned short u) {
    return __bfloat162float(__builtin_bit_cast(__hip_bfloat16, u));
}
// pack top-16 bits of two f32 -> [hi16(b) : hi16(a)]  (1 v_perm)
static __device__ __forceinline__ unsigned pack_hi16(float a, float b) {
    return __builtin_amdgcn_perm(__builtin_bit_cast(unsigned, b),
                                 __builtin_bit_cast(unsigned, a), 0x07060302u);
}
static __device__ __forceinline__ float trunc_hi(float v) {
    return __builtin_bit_cast(float, __builtin_bit_cast(unsigned, v) & 0xffff0000u);
}
static __device__ __forceinline__ unsigned cvtpk_bf16(float a, float b) {
    unsigned r;
    asm("v_cvt_pk_bf16_f32 %0, %1, %2" : "=v"(r) : "v"(a), "v"(b));
    return r;   // low16 = bf16(a), high16 = bf16(b)
}

// ---------------- build transposed upper-tri B planes (hi/lo bf16) ----------------
// bt[j2*F + j1] = bw[pair(j1,j2)] if j1<j2 else 0.  64x64 LDS tile transpose:
// coalesced bw reads (j2-contiguous per j1 row), coalesced bt writes.
__global__ __launch_bounds__(256) void build_bt(const float* __restrict__ bw,
                                                unsigned short* __restrict__ bt_hi,
                                                unsigned short* __restrict__ bt_lo) {
    __shared__ unsigned short tH[64][72], tL[64][72];
    const int bx = blockIdx.x & 31;   // j1 tile
    const int by = blockIdx.x >> 5;   // j2 tile
    const int r  = threadIdx.x >> 2;          // 0..63
    const int cg = (threadIdx.x & 3) * 16;    // col-group start
    const bool up = (by >= bx);
    if (up) {
        int j1 = bx * 64 + r;
        long base = (long)j1 * F - (((long)j1 * (j1 + 1)) >> 1) - j1 - 1;
#pragma unroll
        for (int c = 0; c < 16; ++c) {
            int j2 = by * 64 + cg + c;
            float v = (j2 > j1) ? bw[base + j2] : 0.f;
            unsigned short h = bfb(v);
            tH[r][cg + c] = h;
            tL[r][cg + c] = bfb(v - bff(h));
        }
    }
    __syncthreads();
    size_t obase = (size_t)(by * 64 + r) * F + bx * 64 + cg;   // out row j2, cols j1
    uint4 H0 = {0,0,0,0}, H1 = {0,0,0,0}, L0 = {0,0,0,0}, L1 = {0,0,0,0};
    if (up) {
        unsigned oh[16], ol[16];
#pragma unroll
        for (int c = 0; c < 16; ++c) { oh[c] = tH[cg + c][r]; ol[c] = tL[cg + c][r]; }
        H0.x = oh[0] | (oh[1] << 16);  H0.y = oh[2] | (oh[3] << 16);
        H0.z = oh[4] | (oh[5] << 16);  H0.w = oh[6] | (oh[7] << 16);
        H1.x = oh[8] | (oh[9] << 16);  H1.y = oh[10] | (oh[11] << 16);
        H1.z = oh[12] | (oh[13] << 16); H1.w = oh[14] | (oh[15] << 16);
        L0.x = ol[0] | (ol[1] << 16);  L0.y = ol[2] | (ol[3] << 16);
        L0.z = ol[4] | (ol[5] << 16);  L0.w = ol[6] | (ol[7] << 16);
        L1.x = ol[8] | (ol[9] << 16);  L1.y = ol[10] | (ol[11] << 16);
        L1.z = ol[12] | (ol[13] << 16); L1.w = ol[14] | (ol[15] << 16);
    }
    *(uint4*)(bt_hi + obase)     = H0;
    *(uint4*)(bt_hi + obase + 8) = H1;
    *(uint4*)(bt_lo + obase)     = L0;
    *(uint4*)(bt_lo + obase + 8) = L1;
}

// ---------------- main GEMM: y = x * B (upper-tri), fused epilogue ----------------
// 256x256 tile, BK=32, 8 waves (2x4), double-buffered LDS (128 KiB), paired-row
// swizzle: plane = [128 row-pairs][8 slots x 16B]; slot s of pair rp holds
// (row = 2rp + h>>2, kchunk = h&3) with h = s ^ (rp&7).
__global__ __launch_bounds__(THREADS, 2) void poly2_gemm(
        const float* __restrict__ x,
        const unsigned short* __restrict__ bt_hi,
        const unsigned short* __restrict__ bt_lo,
        const float* __restrict__ w,
        float* __restrict__ cross_acc) {
    extern __shared__ unsigned short smem[];   // [2 buf][4 planes][PL]

    const int tid  = threadIdx.x;
    const int lane = tid & 63;
    const int wid  = tid >> 6;         // 0..7
    const int wm   = wid >> 2;         // 0..1 : 128-row band
    const int wn   = wid & 3;          // 0..3 : 64-col band
    const int lr   = lane & 15;
    const int lg   = lane >> 4;

    // pair heavy nt with light nt so each CU's 2 blocks sum to equal work
    const int g  = blockIdx.x >> 6;
    const int nt = (g < 4) ? (7 - g) : (g - 4);
    const int mt = blockIdx.x & 63;
    const int m0 = mt * BM;
    const int n0 = nt * BN;
    const int ktiles = 8 * (nt + 1);   // triangular skip: kt*32 < (nt+1)*256

    f32x4 acc[8][4] = {};

    auto stageB = [&](int buf, int k0) {
        unsigned short* Bh = smem + buf * 4 * PL + 2 * PL;
        unsigned short* Bl = Bh + PL;
#pragma unroll
        for (int it = 0; it < 2; ++it) {
            int q  = it * THREADS + tid;
            int rp = q >> 3, s = q & 7;
            int h  = s ^ (rp & 7);
            int col  = n0 + 2 * rp + (h >> 2);
            int koff = k0 + (h & 3) * 8;
            const unsigned short* ghi = bt_hi + (size_t)col * F + koff;
            const unsigned short* glo = bt_lo + (size_t)col * F + koff;
            unsigned short* dh = Bh + (q & ~63) * 8;   // wave-uniform base + lane*16B
            unsigned short* dl = Bl + (q & ~63) * 8;
            __builtin_amdgcn_global_load_lds(
                (const __attribute__((address_space(1))) unsigned int*)ghi,
                (__attribute__((address_space(3))) unsigned int*)dh, 16, 0, 0);
            __builtin_amdgcn_global_load_lds(
                (const __attribute__((address_space(1))) unsigned int*)glo,
                (__attribute__((address_space(3))) unsigned int*)dl, 16, 0, 0);
        }
    };
    auto loadA = [&](int k0, float4* raw) {
#pragma unroll
        for (int hf = 0; hf < 2; ++hf) {
            int q  = hf * THREADS + tid;
            int rp = q >> 3, s = q & 7;
            int h  = s ^ (rp & 7);
            const float* src = x + (size_t)(m0 + 2 * rp + (h >> 2)) * F + k0 + (h & 3) * 8;
            raw[hf * 2 + 0] = ((const float4*)src)[0];
            raw[hf * 2 + 1] = ((const float4*)src)[1];
        }
    };
    auto writeA = [&](int buf, const float4* raw) {
        unsigned short* Ah = smem + buf * 4 * PL;
        unsigned short* Al = Ah + PL;
#pragma unroll
        for (int hf = 0; hf < 2; ++hf) {
            int q = hf * THREADS + tid;
            float e0 = raw[hf*2].x, e1 = raw[hf*2].y, e2 = raw[hf*2].z, e3 = raw[hf*2].w;
            float e4 = raw[hf*2+1].x, e5 = raw[hf*2+1].y, e6 = raw[hf*2+1].z, e7 = raw[hf*2+1].w;
            uint4 H, L;
            H.x = pack_hi16(e0, e1); H.y = pack_hi16(e2, e3);
            H.z = pack_hi16(e4, e5); H.w = pack_hi16(e6, e7);
            L.x = cvtpk_bf16(e0 - trunc_hi(e0), e1 - trunc_hi(e1));
            L.y = cvtpk_bf16(e2 - trunc_hi(e2), e3 - trunc_hi(e3));
            L.z = cvtpk_bf16(e4 - trunc_hi(e4), e5 - trunc_hi(e5));
            L.w = cvtpk_bf16(e6 - trunc_hi(e6), e7 - trunc_hi(e7));
            *(uint4*)&Ah[q * 8] = H;   // linear dest: conflict-free
            *(uint4*)&Al[q * 8] = L;
        }
    };
    auto compute = [&](int buf) {
        const unsigned short* Ah = smem + buf * 4 * PL;
        const unsigned short* Al = Ah + PL;
        const unsigned short* Bh = Al + PL;
        const unsigned short* Bl = Bh + PL;
        bf16x8 bh[4], bl[4];
#pragma unroll
        for (int n = 0; n < 4; ++n) {
            int c  = wn * 64 + n * 16 + lr;
            int rp = c >> 1;
            int off = rp * 64 + ((((c & 1) << 2) + lg) ^ (rp & 7)) * 8;
            bh[n] = *(const bf16x8*)&Bh[off];
            bl[n] = *(const bf16x8*)&Bl[off];
        }
#pragma unroll
        for (int mh = 0; mh < 2; ++mh) {
            bf16x8 ah[4], al[4];
#pragma unroll
            for (int m2 = 0; m2 < 4; ++m2) {
                int r  = wm * 128 + (mh * 4 + m2) * 16 + lr;
                int rp = r >> 1;
                int off = rp * 64 + ((((r & 1) << 2) + lg) ^ (rp & 7)) * 8;
                ah[m2] = *(const bf16x8*)&Ah[off];
                al[m2] = *(const bf16x8*)&Al[off];
            }
#pragma unroll
            for (int m2 = 0; m2 < 4; ++m2)
#pragma unroll
                for (int n = 0; n < 4; ++n) {
                    f32x4 c0 = acc[mh * 4 + m2][n];
                    c0 = __builtin_amdgcn_mfma_f32_16x16x32_bf16(ah[m2], bh[n], c0, 0, 0, 0);
                    c0 = __builtin_amdgcn_mfma_f32_16x16x32_bf16(ah[m2], bl[n], c0, 0, 0, 0);
                    c0 = __builtin_amdgcn_mfma_f32_16x16x32_bf16(al[m2], bh[n], c0, 0, 0, 0);
                    acc[mh * 4 + m2][n] = c0;
                }
        }
    };

    // ---- prologue: fill buf 0 ----
    {
        float4 raw[4];
        stageB(0, 0);
        loadA(0, raw);
        writeA(0, raw);
    }
    __syncthreads();

    int cur = 0;
    for (int kt = 0; kt < ktiles; ++kt) {
        const bool more = (kt + 1) < ktiles;
        float4 raw[4];
        if (more) {                                // issue next-tile loads early (T14)
            stageB(cur ^ 1, (kt + 1) * BK);
            loadA((kt + 1) * BK, raw);
        }
        compute(cur);                              // 96 MFMA/wave hide the latency
        if (more) writeA(cur ^ 1, raw);            // convert + LDS-write late
        __syncthreads();                           // drains DMA + loads; buf ready
        cur ^= 1;
    }

    // ---- epilogue: (y + w) dot x per row, 16-lane shuffle reduce, atomic accumulate ----
#pragma unroll
    for (int m = 0; m < 8; ++m) {
#pragma unroll
        for (int r = 0; r < 4; ++r) {
            int grow = m0 + wm * 128 + m * 16 + lg * 4 + r;
            float sum = 0.f;
#pragma unroll
            for (int n = 0; n < 4; ++n) {
                int gcol = n0 + wn * 64 + n * 16 + lr;
                float yv = acc[m][n][r] + w[gcol];
                sum += yv * x[(size_t)grow * F + gcol];
            }
            sum += __shfl_xor(sum, 1);
            sum += __shfl_xor(sum, 2);
            sum += __shfl_xor(sum, 4);
            sum += __shfl_xor(sum, 8);
            if (lr == 0) atomicAdd(&cross_acc[grow], sum);
        }
    }
}

// ---------------- final sigmoid ----------------
__global__ __launch_bounds__(256) void finish_sigmoid(const float* __restrict__ cross,
                                                      const float* __restrict__ w0,
                                                      float* __restrict__ out) {
    int b = blockIdx.x * 256 + threadIdx.x;
    float z = cross[b] + w0[0];
    out[b] = 1.f / (1.f + expf(-z));
}

extern "C" void kernel_launch(void* const* d_in, const int* in_sizes, int n_in,
                              void* d_out, int out_size, void* d_ws, size_t ws_size,
                              hipStream_t stream) {
    const float* x  = (const float*)d_in[0];
    const float* w0 = (const float*)d_in[1];
    const float* w  = (const float*)d_in[2];
    const float* bw = (const float*)d_in[3];
    float* out = (float*)d_out;

    // ws layout: [cross_acc: MBATCH f32][bt_hi: F*F bf16][bt_lo: F*F bf16]  (~16.9 MB)
    float* cross = (float*)d_ws;
    unsigned short* bt_hi = (unsigned short*)((char*)d_ws + (size_t)MBATCH * sizeof(float));
    unsigned short* bt_lo = bt_hi + (size_t)F * F;

    // allow 128 KiB dynamic LDS (idempotent; safe under graph capture)
    hipFuncSetAttribute((const void*)poly2_gemm,
                        hipFuncAttributeMaxDynamicSharedMemorySize, 131072);

    hipMemsetAsync(cross, 0, (size_t)MBATCH * sizeof(float), stream);
    build_bt<<<(F / 64) * (F / 64), 256, 0, stream>>>(bw, bt_hi, bt_lo);
    poly2_gemm<<<(MBATCH / BM) * (F / BN), THREADS, 131072, stream>>>(x, bt_hi, bt_lo, w, cross);
    finish_sigmoid<<<MBATCH / 256, 256, 0, stream>>>(cross, w0, out);
}